// Round 2
// baseline (185.361 us; speedup 1.0000x reference)
//
#include <hip/hip_runtime.h>

// XingLoss: x_list (P=16384, N=1024, 2) f32, scale (int scalar).
// Per row p, per segment s in [0,256): uses points x[3s..3s+3] (max idx 768).
//   v1 = x[3s+1]-x[3s]; v2 = x[3s+2]-x[3s+1]; v3 = x[3s+3]-x[3s+2]
//   direct = cross(v1,v2) >= 0
//   sina   = cross(v1,v3) / (|v1||v3|)
//   term   = direct ? relu(-sina) : relu(sina)
// out = scale * sum(term) / (segn * P)
//
// Journal:
//  R1->R2: same-address atomics removed (215us -> 182.5).
//  R2->R3: 8-rows/block + async global_load_lds dbuf: NEUTRAL (184.5).
//    Two different LDS-staged structures identical => staging is not the
//    lever. Decomposition: fills 156.5us (harness poison, fixed) +
//    partial ~21us + reduce/gaps ~5us. 21us over 101MB = 4.8 TB/s, vs
//    6.85 TB/s the fills prove achievable.
//  R3->R4 (this): LDS has NO reuse here (each float feeds ~1 thread) --
//    the stage->vmcnt-drain->barrier convoy per row is pure overhead
//    (Common-mistake #7). Direct per-thread float2 loads, grid-stride,
//    no barriers in the hot loop: lanes stride 24B so each wave load
//    instruction covers a fully-used 1536B span; L1 absorbs the
//    boundary-point overlap. 8 independent segs/thread x 4 loads =
//    deep MLP. Predict partial ~16-17us, total ~176.

#define N_PTS 1024
#define SEGN  (N_PTS / 4)     // 256 segments per row
#define BLOCK 256
#define GRID  2048            // 8 blocks/CU; gsz = 524288 threads

__global__ __launch_bounds__(BLOCK)
void xing_partial_kernel(const float* __restrict__ x,
                         float*       __restrict__ partial,
                         int total_segs)
{
    const int t   = threadIdx.x;
    const int tid = blockIdx.x * BLOCK + t;
    const int gsz = gridDim.x * BLOCK;

    const float2* __restrict__ pts = reinterpret_cast<const float2*>(x);

    float acc = 0.0f;

    // total_segs = P*SEGN = 4,194,304; gsz = 524,288 -> exactly 8 iters.
    // Consecutive tids cover consecutive segments of one row: each block
    // iteration spans exactly one row (256 segs); wave lanes stride 24B.
    #pragma unroll 4
    for (int g = tid; g < total_segs; g += gsz) {
        const int p = g >> 8;             // row   (SEGN == 256)
        const int s = g & (SEGN - 1);     // segment in row
        const float2* bp = pts + (p * (N_PTS) + 3 * s);   // float2 index

        const float2 a = bp[0];
        const float2 b = bp[1];
        const float2 c = bp[2];
        const float2 d = bp[3];

        const float v1x = b.x - a.x, v1y = b.y - a.y;
        const float v2x = c.x - b.x, v2y = c.y - b.y;
        const float v3x = d.x - c.x, v3y = d.y - c.y;

        const float cross12 = v1x * v2y - v1y * v2x;
        const float cross13 = v1x * v3y - v1y * v3x;

        const float n1 = v1x * v1x + v1y * v1y;
        const float n3 = v3x * v3x + v3y * v3y;
        const float sina = cross13 * rsqrtf(n1 * n3);

        acc += (cross12 >= 0.0f) ? fmaxf(-sina, 0.0f) : fmaxf(sina, 0.0f);
    }

    // Block reduction: wave-64 shuffle, then 4 wave sums via LDS.
    #pragma unroll
    for (int off = 32; off > 0; off >>= 1)
        acc += __shfl_down(acc, off, 64);

    __shared__ float wsum[BLOCK / 64];
    const int lane = t & 63;
    const int wid  = t >> 6;
    if (lane == 0) wsum[wid] = acc;
    __syncthreads();

    if (t == 0)
        partial[blockIdx.x] = (wsum[0] + wsum[1]) + (wsum[2] + wsum[3]);
}

// Reduce nblk partials -> single scalar. nblk = 2048 -> 8KB read.
__global__ __launch_bounds__(BLOCK)
void xing_reduce_kernel(const float* __restrict__ partial,
                        const int*   __restrict__ scale_p,
                        float*       __restrict__ out,
                        int nblk, int P)
{
    const int t = threadIdx.x;
    const float4* pf4 = reinterpret_cast<const float4*>(partial);
    const int nf4 = nblk / 4;   // 512

    float sum = 0.0f;
    for (int i = t; i < nf4; i += BLOCK) {
        float4 v = pf4[i];
        sum += (v.x + v.y) + (v.z + v.w);
    }

    #pragma unroll
    for (int off = 32; off > 0; off >>= 1)
        sum += __shfl_down(sum, off, 64);

    __shared__ float wsum[BLOCK / 64];
    const int lane = t & 63;
    const int wid  = t >> 6;
    if (lane == 0) wsum[wid] = sum;
    __syncthreads();

    if (t == 0) {
        const float total = (wsum[0] + wsum[1]) + (wsum[2] + wsum[3]);
        out[0] = total * (float)(*scale_p) / ((float)SEGN * (float)P);
    }
}

extern "C" void kernel_launch(void* const* d_in, const int* in_sizes, int n_in,
                              void* d_out, int out_size, void* d_ws, size_t ws_size,
                              hipStream_t stream)
{
    const float* x       = (const float*)d_in[0];
    const int*   scale_p = (const int*)d_in[1];
    float*       out     = (float*)d_out;
    float*       partial = (float*)d_ws;

    const int P = in_sizes[0] / (N_PTS * 2);   // 16384 (element count)
    const int total_segs = P * SEGN;           // 4,194,304

    xing_partial_kernel<<<GRID, BLOCK, 0, stream>>>(x, partial, total_segs);
    xing_reduce_kernel<<<1, BLOCK, 0, stream>>>(partial, scale_p, out, GRID, P);
}